// Round 3
// baseline (1690.381 us; speedup 1.0000x reference)
//
#include <hip/hip_runtime.h>

// ---------------------------------------------------------------------------
// Segment mean aggregator:
//   means[v]   = mean of messages[i] where node_ids[i]==v   (0 if empty)
//   last_ts[v] = timestamps[argmax_i{i : node_ids[i]==v}]   (0 if empty)
//   present[v] = 1.0 if any message, else 0.0
// Strategy: build CSR (counts -> exclusive scan -> scatter indices), then
// gather-reduce one wave per node (2 rows/iter, float4 = 16B/lane), no fp32
// atomics anywhere. Messages (1.02 GB) are read exactly once, coalesced.
// ---------------------------------------------------------------------------

__global__ void init_kernel(int* __restrict__ counts, int* __restrict__ cursor,
                            int* __restrict__ last_idx, int V) {
    int i = blockIdx.x * blockDim.x + threadIdx.x;
    if (i < V) {
        counts[i]   = 0;
        cursor[i]   = 0;
        last_idx[i] = -1;
    }
}

// int4-vectorized: 16B/lane id reads; 4 atomics per thread (independent).
__global__ void count_kernel(const int* __restrict__ node_ids,
                             int* __restrict__ counts,
                             int* __restrict__ last_idx, int M) {
    int t = blockIdx.x * blockDim.x + threadIdx.x;
    int base = t * 4;
    if (base + 3 < M) {
        int4 v = *(const int4*)(node_ids + base);
        atomicAdd(&counts[v.x], 1); atomicMax(&last_idx[v.x], base + 0);
        atomicAdd(&counts[v.y], 1); atomicMax(&last_idx[v.y], base + 1);
        atomicAdd(&counts[v.z], 1); atomicMax(&last_idx[v.z], base + 2);
        atomicAdd(&counts[v.w], 1); atomicMax(&last_idx[v.w], base + 3);
    } else {
        for (int i = base; i < M; ++i) {
            int v = node_ids[i];
            atomicAdd(&counts[v], 1); atomicMax(&last_idx[v], i);
        }
    }
}

// Single-block exclusive scan over n ints (n ~ 100K), 4 elements/thread.
// Wave-level shfl scan + 16-wave LDS combine; 25 chunks of 4096.
__global__ void __launch_bounds__(1024)
scan_kernel(const int* __restrict__ counts, int* __restrict__ offsets, int n) {
    __shared__ int wsum[17];
    __shared__ int s_carry;
    const int tid  = threadIdx.x;
    const int lane = tid & 63;
    const int wid  = tid >> 6;   // 0..15
    if (tid == 0) s_carry = 0;
    __syncthreads();
    for (int base = 0; base < n; base += 4096) {
        int i = base + tid * 4;
        int c0 = (i + 0 < n) ? counts[i + 0] : 0;
        int c1 = (i + 1 < n) ? counts[i + 1] : 0;
        int c2 = (i + 2 < n) ? counts[i + 2] : 0;
        int c3 = (i + 3 < n) ? counts[i + 3] : 0;
        int s1 = c0 + c1, s2 = s1 + c2, tsum = s2 + c3;
        int x = tsum;
        #pragma unroll
        for (int d = 1; d < 64; d <<= 1) {
            int t = __shfl_up(x, d, 64);
            if (lane >= d) x += t;
        }
        if (lane == 63) wsum[wid] = x;       // wave inclusive total
        __syncthreads();
        if (tid == 0) {
            int s = 0;
            #pragma unroll
            for (int w = 0; w < 16; ++w) { int t = wsum[w]; wsum[w] = s; s += t; }
            wsum[16] = s;                    // chunk total
        }
        __syncthreads();
        int tbase = (x - tsum) + wsum[wid] + s_carry;   // exclusive at i
        if (i + 0 < n) offsets[i + 0] = tbase;
        if (i + 1 < n) offsets[i + 1] = tbase + c0;
        if (i + 2 < n) offsets[i + 2] = tbase + s1;
        if (i + 3 < n) offsets[i + 3] = tbase + s2;
        __syncthreads();                     // all reads of s_carry done
        if (tid == 0) s_carry += wsum[16];
        __syncthreads();
    }
}

// int4-vectorized scatter of message indices into CSR order.
__global__ void scatter_kernel(const int* __restrict__ node_ids,
                               const int* __restrict__ offsets,
                               int* __restrict__ cursor,
                               int* __restrict__ msg_idx, int M) {
    int t = blockIdx.x * blockDim.x + threadIdx.x;
    int base = t * 4;
    if (base + 3 < M) {
        int4 v = *(const int4*)(node_ids + base);
        int p0 = atomicAdd(&cursor[v.x], 1);
        int p1 = atomicAdd(&cursor[v.y], 1);
        int p2 = atomicAdd(&cursor[v.z], 1);
        int p3 = atomicAdd(&cursor[v.w], 1);
        msg_idx[offsets[v.x] + p0] = base + 0;
        msg_idx[offsets[v.y] + p1] = base + 1;
        msg_idx[offsets[v.z] + p2] = base + 2;
        msg_idx[offsets[v.w] + p3] = base + 3;
    } else {
        for (int i = base; i < M; ++i) {
            int v = node_ids[i];
            int p = atomicAdd(&cursor[v], 1);
            msg_idx[offsets[v] + p] = i;
        }
    }
}

// One wave per node. Two rows per iteration: lanes 0-31 -> row j (float4),
// lanes 32-63 -> row j+1. Index prefetched one iteration ahead so the row
// gather never serializes behind its index load. Final __shfl_xor(,32)
// folds the two half-wave accumulators.
__global__ void __launch_bounds__(256)
mean_kernel(const float* __restrict__ messages,
            const float* __restrict__ timestamps,
            const int* __restrict__ counts,
            const int* __restrict__ offsets,
            const int* __restrict__ last_idx,
            const int* __restrict__ msg_idx,
            float* __restrict__ means,
            float* __restrict__ last_ts,
            float* __restrict__ present,
            int V) {
    int gwave = (blockIdx.x * blockDim.x + threadIdx.x) >> 6;
    int lane  = threadIdx.x & 63;
    if (gwave >= V) return;
    const int v    = gwave;
    const int cnt  = counts[v];
    const int off  = offsets[v];
    const int half = lane >> 5;   // 0 or 1: which row of the pair
    const int sub  = lane & 31;   // float4 column index

    float ax = 0.f, ay = 0.f, az = 0.f, aw = 0.f;
    const int* mi = msg_idx + off;
    int j   = half;
    int idx = (j < cnt) ? mi[j] : 0;
    while (j < cnt) {
        int jn   = j + 2;
        int idxn = (jn < cnt) ? mi[jn] : 0;        // prefetch next index
        const float4* row = (const float4*)(messages + (size_t)idx * 128);
        float4 m = row[sub];
        ax += m.x; ay += m.y; az += m.z; aw += m.w;
        idx = idxn;
        j = jn;
    }
    // fold the two half-wave accumulators
    ax += __shfl_xor(ax, 32);
    ay += __shfl_xor(ay, 32);
    az += __shfl_xor(az, 32);
    aw += __shfl_xor(aw, 32);

    const float inv = (cnt > 0) ? (1.0f / (float)cnt) : 0.0f;
    if (half == 0) {
        float4 out;
        out.x = ax * inv; out.y = ay * inv; out.z = az * inv; out.w = aw * inv;
        ((float4*)(means + (size_t)v * 128))[sub] = out;
    }
    if (lane == 0) {
        last_ts[v] = (cnt > 0) ? timestamps[last_idx[v]] : 0.0f;
        present[v] = (cnt > 0) ? 1.0f : 0.0f;
    }
}

extern "C" void kernel_launch(void* const* d_in, const int* in_sizes, int n_in,
                              void* d_out, int out_size, void* d_ws, size_t ws_size,
                              hipStream_t stream) {
    const float* messages   = (const float*)d_in[0];
    const float* timestamps = (const float*)d_in[1];
    const int*   node_ids   = (const int*)d_in[2];

    const int M = in_sizes[1];            // number of messages
    const int V = out_size / 130;         // 128 mean cols + last_ts + present

    // Output layout: [V*128 means][V last_ts][V present]
    float* means   = (float*)d_out;
    float* last_ts = means + (size_t)V * 128;
    float* present = last_ts + V;

    // Workspace layout (ints): counts | offsets | cursor | last_idx | msg_idx[M]
    int* counts   = (int*)d_ws;
    int* offsets  = counts + V;
    int* cursor   = offsets + V;
    int* last_idx = cursor + V;
    int* msg_idx  = last_idx + V;

    const int B = 256;

    hipLaunchKernelGGL(init_kernel, dim3((V + B - 1) / B), dim3(B), 0, stream,
                       counts, cursor, last_idx, V);

    const int M4 = (M + 3) / 4;   // threads for int4-vectorized passes
    hipLaunchKernelGGL(count_kernel, dim3((M4 + B - 1) / B), dim3(B), 0, stream,
                       node_ids, counts, last_idx, M);

    hipLaunchKernelGGL(scan_kernel, dim3(1), dim3(1024), 0, stream,
                       counts, offsets, V);

    hipLaunchKernelGGL(scatter_kernel, dim3((M4 + B - 1) / B), dim3(B), 0, stream,
                       node_ids, offsets, cursor, msg_idx, M);

    // one wave per node, 4 waves per 256-thread block
    const int wavesPerBlock = B / 64;
    hipLaunchKernelGGL(mean_kernel, dim3((V + wavesPerBlock - 1) / wavesPerBlock),
                       dim3(B), 0, stream,
                       messages, timestamps, counts, offsets, last_idx, msg_idx,
                       means, last_ts, present, V);
}